// Round 11
// baseline (444.462 us; speedup 1.0000x reference)
//
#include <hip/hip_runtime.h>
#include <hip/hip_bf16.h>
#include <stdint.h>

#define N_NODES 50000
#define N_EDGES 800000
#define IN_DIM 64
#define HID 128
#define OUT_DIM 64
#define T_HIST 8

#define NB_SCAN ((N_NODES + 1023) / 1024)   // 49 scan blocks, 1024 nodes each

typedef __attribute__((ext_vector_type(8))) short short8;
typedef __attribute__((ext_vector_type(4))) float f32x4;

__device__ __forceinline__ unsigned short f2bf(float x) {
  unsigned int u = __builtin_bit_cast(unsigned int, x);
  unsigned int r = (u + 0x7FFFu + ((u >> 16) & 1u)) >> 16;
  return (unsigned short)r;
}
__device__ __forceinline__ short8 cvt8(float4 a, float4 b) {
  unsigned int w0, w1, w2, w3;
  asm("v_cvt_pk_bf16_f32 %0, %1, %2" : "=v"(w0) : "v"(a.x), "v"(a.y));
  asm("v_cvt_pk_bf16_f32 %0, %1, %2" : "=v"(w1) : "v"(a.z), "v"(a.w));
  asm("v_cvt_pk_bf16_f32 %0, %1, %2" : "=v"(w2) : "v"(b.x), "v"(b.y));
  asm("v_cvt_pk_bf16_f32 %0, %1, %2" : "=v"(w3) : "v"(b.z), "v"(b.w));
  struct { unsigned int a, b, c, d; } s{w0, w1, w2, w3};
  return __builtin_bit_cast(short8, s);
}
// sigmoid/tanh via exp2+rcp; safe at +-inf
__device__ __forceinline__ float sigm(float x) {
  float e = __builtin_amdgcn_exp2f(-1.4426950408889634f * x);
  return __builtin_amdgcn_rcpf(1.f + e);
}
__device__ __forceinline__ float tanh_f(float x) {
  float e = __builtin_amdgcn_exp2f(2.8853900817779268f * x);
  return 1.f - 2.f * __builtin_amdgcn_rcpf(e + 1.f);
}

// ---------------- prepack + count (R9 verbatim) ----------------
__global__ void pc_kernel(const float* __restrict__ w_ih, const float* __restrict__ w_hh,
                          const float* __restrict__ W_cls,
                          const float* __restrict__ W_self, const float* __restrict__ W_neigh,
                          const float* __restrict__ b_sage, const float* __restrict__ b_cls,
                          const int* __restrict__ dst,
                          unsigned short* __restrict__ Wt2, unsigned short* __restrict__ Wc2,
                          float* __restrict__ Wsc, float* __restrict__ Wnc,
                          float* __restrict__ bc1, int* __restrict__ cnt) {
  int tid = blockIdx.x * blockDim.x + threadIdx.x;
  int stride = gridDim.x * blockDim.x;
  for (int e = tid; e < N_EDGES; e += stride) atomicAdd(&cnt[dst[e]], 1);
  for (int idx = tid; idx < 256 * 512; idx += stride) {
    int i = idx & 7;
    int lane = (idx >> 3) & 63;
    int F = idx >> 9;
    int q = F >> 5, g = (F >> 3) & 3, kk = F & 7;
    int c = g * 128 + q * 16 + (lane & 15);
    int k = kk * 32 + (lane >> 4) * 8 + i;
    float v = (k < 128) ? w_ih[k * 512 + c] : w_hh[(k - 128) * 512 + c];
    Wt2[idx] = f2bf(v);
  }
  for (int idx = tid; idx < 16 * 512; idx += stride) {
    int i = idx & 7;
    int lane = (idx >> 3) & 63;
    int F = idx >> 9;
    int cb = F >> 2, kk = F & 3;
    int col = cb * 16 + (lane & 15);
    int k = kk * 32 + (lane >> 4) * 8 + i;
    Wc2[idx] = f2bf(W_cls[k * 64 + col]);
  }
  for (int idx = tid; idx < 64 * 64; idx += stride) {
    int k = idx >> 6, c = idx & 63;
    float as = 0.f, an = 0.f;
    for (int m = 0; m < 128; m++) {
      float wc = W_cls[m * 64 + c];
      as += W_self[k * 128 + m] * wc;
      an += W_neigh[k * 128 + m] * wc;
    }
    Wsc[idx] = as;
    Wnc[idx] = an;
  }
  for (int c = tid; c < 64; c += stride) {
    float acc = b_cls[c];
    for (int m = 0; m < 128; m++) acc += b_sage[m] * W_cls[m * 64 + c];
    bc1[c] = acc;
  }
}

// ---------------- scan1 (R9 verbatim) ----------------
__global__ __launch_bounds__(256) void scan1_kernel(const int* __restrict__ cnt,
                                                    int* __restrict__ lexcl, int* __restrict__ btot) {
  __shared__ int sh[256];
  int tid = threadIdx.x;
  int base = blockIdx.x * 1024 + tid * 4;
  int v[4];
  #pragma unroll
  for (int q = 0; q < 4; q++) {
    int i = base + q;
    v[q] = (i < N_NODES) ? cnt[i] : 0;
  }
  int tsum = v[0] + v[1] + v[2] + v[3];
  sh[tid] = tsum;
  __syncthreads();
  int val = tsum;
  for (int off = 1; off < 256; off <<= 1) {
    int x = (tid >= off) ? sh[tid - off] : 0;
    __syncthreads();
    val += x;
    sh[tid] = val;
    __syncthreads();
  }
  int ex = val - tsum;
  if (tid == 255) btot[blockIdx.x] = val;
  #pragma unroll
  for (int q = 0; q < 4; q++) {
    int i = base + q;
    if (i < N_NODES) lexcl[i] = ex;
    ex += v[q];
  }
}

// ---------------- scan3 (R9 verbatim) ----------------
__global__ __launch_bounds__(1024) void scan3_kernel(const int* __restrict__ lexcl,
                                                     const int* __restrict__ btot,
                                                     int* __restrict__ rowstart, int* __restrict__ cursor) {
  int b = blockIdx.x;
  int bs = 0;
  for (int j = 0; j < b; j++) bs += btot[j];
  int i = b * 1024 + threadIdx.x;
  if (i < N_NODES) {
    int rs = lexcl[i] + bs;
    rowstart[i] = rs;
    cursor[i] = rs;
  }
}

// ---------------- fill (R9 verbatim) ----------------
__global__ void fill_kernel(const int* __restrict__ src, const int* __restrict__ dst,
                            int* __restrict__ cursor, int* __restrict__ esrc) {
  int e = blockIdx.x * blockDim.x + threadIdx.x;
  if (e < N_EDGES) {
    int d = dst[e];
    int pos = atomicAdd(&cursor[d], 1);
    esrc[pos] = src[e];
  }
}

// ---------------- hstruct (R9 verbatim): out1 = nf@Wsc + mean_neigh@Wnc + bc1 ----------------
#define HS_TILE 32
__global__ __launch_bounds__(512) void hstruct_kernel(
    const float* __restrict__ nf, const int* __restrict__ esrc,
    const int* __restrict__ rowstart, const int* __restrict__ cnt,
    const float* __restrict__ Wsc, const float* __restrict__ Wnc, const float* __restrict__ bc1,
    float* __restrict__ out1) {
  __shared__ float s_nf[HS_TILE][IN_DIM + 1];
  __shared__ float s_hn[HS_TILE][IN_DIM + 1];
  int tid = threadIdx.x;
  int node0 = blockIdx.x * HS_TILE;
  for (int i = tid; i < HS_TILE * IN_DIM; i += 512) {
    int r = i >> 6, k = i & 63;
    int node = node0 + r;
    s_nf[r][k] = (node < N_NODES) ? nf[node * 64 + k] : 0.f;
  }
  int wv = tid >> 6, lane = tid & 63;
  for (int r = wv; r < HS_TILE; r += 8) {
    int node = node0 + r;
    float a0 = 0.f, a1 = 0.f, a2 = 0.f, a3 = 0.f;
    int n = 0;
    if (node < N_NODES) {
      n = cnt[node];
      int st = rowstart[node];
      int j = 0;
      for (; j + 4 <= n; j += 4) {
        int s0 = esrc[st + j], s1 = esrc[st + j + 1];
        int s2 = esrc[st + j + 2], s3 = esrc[st + j + 3];
        a0 += nf[s0 * 64 + lane];
        a1 += nf[s1 * 64 + lane];
        a2 += nf[s2 * 64 + lane];
        a3 += nf[s3 * 64 + lane];
      }
      for (; j < n; j++) a0 += nf[esrc[st + j] * 64 + lane];
    }
    s_hn[r][lane] = (a0 + a1 + a2 + a3) * __builtin_amdgcn_rcpf(fmaxf((float)n, 1.f));
  }
  __syncthreads();
  int r = tid & 31;
  int c0 = (tid >> 5) * 4;
  float accs[4] = {0.f, 0.f, 0.f, 0.f};
  for (int k = 0; k < IN_DIM; k++) {
    float a = s_nf[r][k];
    float b = s_hn[r][k];
    float4 w1 = *(const float4*)&Wsc[k * 64 + c0];
    float4 w2 = *(const float4*)&Wnc[k * 64 + c0];
    accs[0] += a * w1.x + b * w2.x;
    accs[1] += a * w1.y + b * w2.y;
    accs[2] += a * w1.z + b * w2.z;
    accs[3] += a * w1.w + b * w2.w;
  }
  int node = node0 + r;
  if (node < N_NODES) {
    #pragma unroll
    for (int i = 0; i < 4; i++)
      out1[(size_t)node * 64 + c0 + i] = accs[i] + bc1[c0 + i];
  }
}

// ---------------- fused LSTM + classifier: symmetric gate-split, 1024 thr ----------------
// 16 waves. Wave (q = w>>1, h = w&1): cols jj in [16q,16q+16), gates {2h, 2h+1}.
// Bfr = 64 VGPR -> 4 waves/SIMD. Each team keeps its OWN row-half's pre-acts in
// regs (ownA, 16) and publishes the other half via fp32 Gbuf (bias folded).
// Each thread updates 8 cells (c_st[8]). No xp prefetch. t-loop not unrolled.
#define LB 64
__global__ __launch_bounds__(1024, 4) void lstm_kernel(
    const float* __restrict__ hist,          // [N][8][128] f32
    const unsigned short* __restrict__ Wt2,  // frag-ordered bf16
    const unsigned short* __restrict__ Wc2,  // frag-ordered bf16
    const float* __restrict__ b_lstm,        // [512]
    const float* __restrict__ out1,          // [N][64] fp32 (classifier partial)
    float* __restrict__ out)                 // [N][64]
{
  __shared__ alignas(16) unsigned short Abuf[2][64 * 256];  // 64KB
  __shared__ float Gbuf[2][2][32][132];                     // 66KB, stride 132 kills conflicts

  const int tid = threadIdx.x;
  const int lane = tid & 63;
  const int w = tid >> 6;      // 0..15
  const int q = w >> 1;        // col-group 0..7
  const int h = w & 1;         // gate team: 0 -> {i,f}, 1 -> {g,o}
  const int l15 = lane & 15;
  const int l4 = lane >> 4;
  const int base = blockIdx.x * LB;
  const int jj = q * 16 + l15;

  // persistent B fragments: this team's 2 gates x 8 kk = 64 VGPR
  short8 Bfr[2][8];
  #pragma unroll
  for (int gg = 0; gg < 2; gg++)
    #pragma unroll
    for (int kk = 0; kk < 8; kk++)
      Bfr[gg][kk] = *(const short8*)&Wt2[((q * 32 + (2 * h + gg) * 8 + kk) * 64 + lane) * 8];

  const float bA = b_lstm[(2 * h + 0) * 128 + jj];
  const float bB = b_lstm[(2 * h + 1) * 128 + jj];

  float c_st[8];
  #pragma unroll
  for (int i = 0; i < 8; i++) c_st[i] = 0.f;

  // prologue: zero h-region of buf0 + stage x(0); 1024 threads = 1024 short8 units
  {
    int row = tid >> 4, kb = tid & 15;
    short8 z = {0,0,0,0,0,0,0,0};
    *(short8*)&Abuf[0][row * 256 + 128 + kb * 8] = z;
    int node = base + row;
    float4 x0 = make_float4(0.f,0.f,0.f,0.f), x1 = make_float4(0.f,0.f,0.f,0.f);
    if (node < N_NODES) {
      const float4* p = (const float4*)&hist[(size_t)node * (T_HIST * HID) + kb * 8];
      x0 = p[0]; x1 = p[1];
    }
    int sb = (kb & 8) | ((kb & 7) ^ (row & 7));
    *(short8*)&Abuf[0][row * 256 + sb * 8] = cvt8(x0, x1);
  }
  __syncthreads();

  #pragma unroll 1
  for (int t = 0; t < T_HIST; t++) {
    unsigned short* Acur = &Abuf[t & 1][0];
    unsigned short* Anxt = &Abuf[(t & 1) ^ 1][0];

    f32x4 ownA[2][2];   // own row-half pre-acts: [pass 0/1][gate 0/1]

    // 4 row-block passes over all 64 rows; a0/a1 die per pass
    #pragma unroll
    for (int rb = 0; rb < 4; rb++) {
      f32x4 a0 = {0.f,0.f,0.f,0.f}, a1 = {0.f,0.f,0.f,0.f};
      #pragma unroll
      for (int kk = 0; kk < 8; kk++) {
        int row = rb * 16 + l15;
        int kb = kk * 4 + l4;
        int sb = (kb & 24) | ((kb & 7) ^ (row & 7));
        short8 a = *(const short8*)&Acur[row * 256 + sb * 8];
        a0 = __builtin_amdgcn_mfma_f32_16x16x32_bf16(a, Bfr[0][kk], a0, 0, 0, 0);
        a1 = __builtin_amdgcn_mfma_f32_16x16x32_bf16(a, Bfr[1][kk], a1, 0, 0, 0);
      }
      bool own = (h == 0) ? (rb < 2) : (rb >= 2);   // wave-uniform
      if (own) {
        ownA[rb & 1][0] = a0;
        ownA[rb & 1][1] = a1;
      } else {
        int r32b = (h == 0) ? (rb - 2) * 16 : rb * 16;  // row within other half
        #pragma unroll
        for (int reg = 0; reg < 4; reg++) {
          int r32 = r32b + l4 * 4 + reg;
          Gbuf[h][0][r32][jj] = a0[reg] + bA;   // bias folded at publish
          Gbuf[h][1][r32][jj] = a1[reg] + bB;
        }
      }
      __builtin_amdgcn_sched_barrier(0);
    }
    __syncthreads();   // Gbuf ready

    // cell updates: own half (32 rows x 16 cols per wave -> 8 cells/thread)
    #pragma unroll
    for (int p = 0; p < 2; p++) {
      #pragma unroll
      for (int reg = 0; reg < 4; reg++) {
        int r32 = p * 16 + l4 * 4 + reg;    // row within own half
        int row = h * 32 + r32;             // absolute row
        int ci = p * 4 + reg;
        float o0 = ownA[p][0][reg] + bA;
        float o1 = ownA[p][1][reg] + bB;
        float g0 = Gbuf[1 - h][0][r32][jj]; // partner gates, pre-biased
        float g1 = Gbuf[1 - h][1][r32][jj];
        float gi, gf, gg_, go;
        if (h == 0) { gi = sigm(o0); gf = sigm(o1); gg_ = tanh_f(g0); go = sigm(g1); }
        else        { gi = sigm(g0); gf = sigm(g1); gg_ = tanh_f(o0); go = sigm(o1); }
        float c = gf * c_st[ci] + gi * gg_;
        c_st[ci] = c;
        float hv = go * tanh_f(c);
        if (t < T_HIST - 1) {
          int kb = 16 + (jj >> 3);
          int sb = (kb & 24) | ((kb & 7) ^ (row & 7));
          Anxt[row * 256 + sb * 8 + (jj & 7)] = f2bf(hv);
        } else {
          int kb = jj >> 3;
          int sb = (kb & 8) | ((kb & 7) ^ (row & 7));
          Anxt[row * 256 + sb * 8 + (jj & 7)] = f2bf(hv);
        }
      }
    }
    // stage x(t+1): 1024 threads, one short8 unit each (latency hidden by 16 waves/CU)
    if (t < T_HIST - 1) {
      int row = tid >> 4, kb = tid & 15;
      int node = base + row;
      float4 x0 = make_float4(0.f,0.f,0.f,0.f), x1 = make_float4(0.f,0.f,0.f,0.f);
      if (node < N_NODES) {
        const float4* p = (const float4*)&hist[(size_t)node * (T_HIST * HID) + (t + 1) * HID + kb * 8];
        x0 = p[0]; x1 = p[1];
      }
      int sb = (kb & 8) | ((kb & 7) ^ (row & 7));
      *(short8*)&Anxt[row * 256 + sb * 8] = cvt8(x0, x1);
    }
    __syncthreads();   // Anxt complete
  }

  // ---------------- classifier: out = h_temp @ W_cls + out1; one frag per wave ----------------
  {
    const unsigned short* Afin = &Abuf[0][0];   // t=7 wrote Anxt = Abuf[0] x-region
    int rbo = w >> 2, cbo = w & 3;
    int col = cbo * 16 + l15;
    float ov[4];
    #pragma unroll
    for (int reg = 0; reg < 4; reg++) {
      int row = rbo * 16 + l4 * 4 + reg;
      int node = base + row;
      ov[reg] = (node < N_NODES) ? out1[(size_t)node * OUT_DIM + col] : 0.f;
    }
    f32x4 o = {0.f, 0.f, 0.f, 0.f};
    #pragma unroll
    for (int kk = 0; kk < 4; kk++) {
      short8 bv = *(const short8*)&Wc2[((cbo * 4 + kk) * 64 + lane) * 8];
      int row = rbo * 16 + l15;
      int kb = kk * 4 + l4;
      int sb = (kb & 8) | ((kb & 7) ^ (row & 7));
      short8 a = *(const short8*)&Afin[row * 256 + sb * 8];
      o = __builtin_amdgcn_mfma_f32_16x16x32_bf16(a, bv, o, 0, 0, 0);
    }
    #pragma unroll
    for (int reg = 0; reg < 4; reg++) {
      int row = rbo * 16 + l4 * 4 + reg;
      int node = base + row;
      if (node < N_NODES) out[(size_t)node * OUT_DIM + col] = o[reg] + ov[reg];
    }
  }
}

// ---------------- launch ----------------
extern "C" void kernel_launch(void* const* d_in, const int* in_sizes, int n_in,
                              void* d_out, int out_size, void* d_ws, size_t ws_size,
                              hipStream_t stream) {
  (void)in_sizes; (void)n_in; (void)out_size; (void)ws_size;
  const float* node_feats = (const float*)d_in[0];
  const float* hist       = (const float*)d_in[1];
  const int*   src        = (const int*)d_in[2];
  const int*   dst        = (const int*)d_in[3];
  const float* W_self     = (const float*)d_in[4];
  const float* W_neigh    = (const float*)d_in[5];
  const float* b_sage     = (const float*)d_in[6];
  const float* w_ih       = (const float*)d_in[7];
  const float* w_hh       = (const float*)d_in[8];
  const float* b_lstm     = (const float*)d_in[9];
  const float* W_cls      = (const float*)d_in[10];
  const float* b_cls      = (const float*)d_in[11];
  float* out = (float*)d_out;

  char* ws = (char*)d_ws;
  int* cnt        = (int*)(ws);                        // 200,192
  int* lexcl      = (int*)(ws + 200192);               // -> 400,384
  int* rowstart   = (int*)(ws + 400384);               // -> 600,576
  int* cursor     = (int*)(ws + 600576);               // -> 800,768
  int* btot       = (int*)(ws + 800768);               // -> 801,792
  int* esrc       = (int*)(ws + 801792);               // -> 4,001,792
  float* out1     = (float*)(ws + 4001792);            // -> 16,801,792
  unsigned short* Wt2 = (unsigned short*)(ws + 16801792);  // -> 17,063,936
  unsigned short* Wc2 = (unsigned short*)(ws + 17063936);  // -> 17,080,320
  float* Wsc      = (float*)(ws + 17080320);           // -> 17,096,704
  float* Wnc      = (float*)(ws + 17096704);           // -> 17,113,088
  float* bc1      = (float*)(ws + 17113088);           // -> 17,113,344

  hipMemsetAsync(cnt, 0, 200000, stream);
  pc_kernel<<<1024, 256, 0, stream>>>(w_ih, w_hh, W_cls, W_self, W_neigh, b_sage, b_cls,
                                      dst, Wt2, Wc2, Wsc, Wnc, bc1, cnt);
  scan1_kernel<<<NB_SCAN, 256, 0, stream>>>(cnt, lexcl, btot);
  scan3_kernel<<<NB_SCAN, 1024, 0, stream>>>(lexcl, btot, rowstart, cursor);
  fill_kernel<<<(N_EDGES + 255) / 256, 256, 0, stream>>>(src, dst, cursor, esrc);
  hstruct_kernel<<<(N_NODES + HS_TILE - 1) / HS_TILE, 512, 0, stream>>>(
      node_feats, esrc, rowstart, cnt, Wsc, Wnc, bc1, out1);
  lstm_kernel<<<(N_NODES + LB - 1) / LB, 1024, 0, stream>>>(
      hist, Wt2, Wc2, b_lstm, out1, out);
}

// Round 12
// 357.794 us; speedup vs baseline: 1.2422x; 1.2422x over previous
//
#include <hip/hip_runtime.h>
#include <hip/hip_bf16.h>
#include <stdint.h>

#define N_NODES 50000
#define N_EDGES 800000
#define IN_DIM 64
#define HID 128
#define OUT_DIM 64
#define T_HIST 8

#define NB_SCAN ((N_NODES + 1023) / 1024)   // 49 scan blocks, 1024 nodes each

typedef __attribute__((ext_vector_type(8))) short short8;
typedef __attribute__((ext_vector_type(4))) float f32x4;

__device__ __forceinline__ unsigned short f2bf(float x) {
  unsigned int u = __builtin_bit_cast(unsigned int, x);
  unsigned int r = (u + 0x7FFFu + ((u >> 16) & 1u)) >> 16;
  return (unsigned short)r;
}
__device__ __forceinline__ short8 cvt8(float4 a, float4 b) {
  unsigned int w0, w1, w2, w3;
  asm("v_cvt_pk_bf16_f32 %0, %1, %2" : "=v"(w0) : "v"(a.x), "v"(a.y));
  asm("v_cvt_pk_bf16_f32 %0, %1, %2" : "=v"(w1) : "v"(a.z), "v"(a.w));
  asm("v_cvt_pk_bf16_f32 %0, %1, %2" : "=v"(w2) : "v"(b.x), "v"(b.y));
  asm("v_cvt_pk_bf16_f32 %0, %1, %2" : "=v"(w3) : "v"(b.z), "v"(b.w));
  struct { unsigned int a, b, c, d; } s{w0, w1, w2, w3};
  return __builtin_bit_cast(short8, s);
}
// sigmoid/tanh via exp2+rcp; safe at +-inf
__device__ __forceinline__ float sigm(float x) {
  float e = __builtin_amdgcn_exp2f(-1.4426950408889634f * x);
  return __builtin_amdgcn_rcpf(1.f + e);
}
__device__ __forceinline__ float tanh_f(float x) {
  float e = __builtin_amdgcn_exp2f(2.8853900817779268f * x);
  return 1.f - 2.f * __builtin_amdgcn_rcpf(e + 1.f);
}

// ---------------- prepack + count (R9 verbatim) ----------------
__global__ void pc_kernel(const float* __restrict__ w_ih, const float* __restrict__ w_hh,
                          const float* __restrict__ W_cls,
                          const float* __restrict__ W_self, const float* __restrict__ W_neigh,
                          const float* __restrict__ b_sage, const float* __restrict__ b_cls,
                          const int* __restrict__ dst,
                          unsigned short* __restrict__ Wt2, unsigned short* __restrict__ Wc2,
                          float* __restrict__ Wsc, float* __restrict__ Wnc,
                          float* __restrict__ bc1, int* __restrict__ cnt) {
  int tid = blockIdx.x * blockDim.x + threadIdx.x;
  int stride = gridDim.x * blockDim.x;
  for (int e = tid; e < N_EDGES; e += stride) atomicAdd(&cnt[dst[e]], 1);
  for (int idx = tid; idx < 256 * 512; idx += stride) {
    int i = idx & 7;
    int lane = (idx >> 3) & 63;
    int F = idx >> 9;
    int q = F >> 5, g = (F >> 3) & 3, kk = F & 7;
    int c = g * 128 + q * 16 + (lane & 15);
    int k = kk * 32 + (lane >> 4) * 8 + i;
    float v = (k < 128) ? w_ih[k * 512 + c] : w_hh[(k - 128) * 512 + c];
    Wt2[idx] = f2bf(v);
  }
  for (int idx = tid; idx < 16 * 512; idx += stride) {
    int i = idx & 7;
    int lane = (idx >> 3) & 63;
    int F = idx >> 9;
    int cb = F >> 2, kk = F & 3;
    int col = cb * 16 + (lane & 15);
    int k = kk * 32 + (lane >> 4) * 8 + i;
    Wc2[idx] = f2bf(W_cls[k * 64 + col]);
  }
  for (int idx = tid; idx < 64 * 64; idx += stride) {
    int k = idx >> 6, c = idx & 63;
    float as = 0.f, an = 0.f;
    for (int m = 0; m < 128; m++) {
      float wc = W_cls[m * 64 + c];
      as += W_self[k * 128 + m] * wc;
      an += W_neigh[k * 128 + m] * wc;
    }
    Wsc[idx] = as;
    Wnc[idx] = an;
  }
  for (int c = tid; c < 64; c += stride) {
    float acc = b_cls[c];
    for (int m = 0; m < 128; m++) acc += b_sage[m] * W_cls[m * 64 + c];
    bc1[c] = acc;
  }
}

// ---------------- scan1 (R9 verbatim) ----------------
__global__ __launch_bounds__(256) void scan1_kernel(const int* __restrict__ cnt,
                                                    int* __restrict__ lexcl, int* __restrict__ btot) {
  __shared__ int sh[256];
  int tid = threadIdx.x;
  int base = blockIdx.x * 1024 + tid * 4;
  int v[4];
  #pragma unroll
  for (int q = 0; q < 4; q++) {
    int i = base + q;
    v[q] = (i < N_NODES) ? cnt[i] : 0;
  }
  int tsum = v[0] + v[1] + v[2] + v[3];
  sh[tid] = tsum;
  __syncthreads();
  int val = tsum;
  for (int off = 1; off < 256; off <<= 1) {
    int x = (tid >= off) ? sh[tid - off] : 0;
    __syncthreads();
    val += x;
    sh[tid] = val;
    __syncthreads();
  }
  int ex = val - tsum;
  if (tid == 255) btot[blockIdx.x] = val;
  #pragma unroll
  for (int q = 0; q < 4; q++) {
    int i = base + q;
    if (i < N_NODES) lexcl[i] = ex;
    ex += v[q];
  }
}

// ---------------- scan3 (R9 verbatim) ----------------
__global__ __launch_bounds__(1024) void scan3_kernel(const int* __restrict__ lexcl,
                                                     const int* __restrict__ btot,
                                                     int* __restrict__ rowstart, int* __restrict__ cursor) {
  int b = blockIdx.x;
  int bs = 0;
  for (int j = 0; j < b; j++) bs += btot[j];
  int i = b * 1024 + threadIdx.x;
  if (i < N_NODES) {
    int rs = lexcl[i] + bs;
    rowstart[i] = rs;
    cursor[i] = rs;
  }
}

// ---------------- fill (R9 verbatim) ----------------
__global__ void fill_kernel(const int* __restrict__ src, const int* __restrict__ dst,
                            int* __restrict__ cursor, int* __restrict__ esrc) {
  int e = blockIdx.x * blockDim.x + threadIdx.x;
  if (e < N_EDGES) {
    int d = dst[e];
    int pos = atomicAdd(&cursor[d], 1);
    esrc[pos] = src[e];
  }
}

// ---------------- hstruct (R9 verbatim): out1 = nf@Wsc + mean_neigh@Wnc + bc1 ----------------
#define HS_TILE 32
__global__ __launch_bounds__(512) void hstruct_kernel(
    const float* __restrict__ nf, const int* __restrict__ esrc,
    const int* __restrict__ rowstart, const int* __restrict__ cnt,
    const float* __restrict__ Wsc, const float* __restrict__ Wnc, const float* __restrict__ bc1,
    float* __restrict__ out1) {
  __shared__ float s_nf[HS_TILE][IN_DIM + 1];
  __shared__ float s_hn[HS_TILE][IN_DIM + 1];
  int tid = threadIdx.x;
  int node0 = blockIdx.x * HS_TILE;
  for (int i = tid; i < HS_TILE * IN_DIM; i += 512) {
    int r = i >> 6, k = i & 63;
    int node = node0 + r;
    s_nf[r][k] = (node < N_NODES) ? nf[node * 64 + k] : 0.f;
  }
  int wv = tid >> 6, lane = tid & 63;
  for (int r = wv; r < HS_TILE; r += 8) {
    int node = node0 + r;
    float a0 = 0.f, a1 = 0.f, a2 = 0.f, a3 = 0.f;
    int n = 0;
    if (node < N_NODES) {
      n = cnt[node];
      int st = rowstart[node];
      int j = 0;
      for (; j + 4 <= n; j += 4) {
        int s0 = esrc[st + j], s1 = esrc[st + j + 1];
        int s2 = esrc[st + j + 2], s3 = esrc[st + j + 3];
        a0 += nf[s0 * 64 + lane];
        a1 += nf[s1 * 64 + lane];
        a2 += nf[s2 * 64 + lane];
        a3 += nf[s3 * 64 + lane];
      }
      for (; j < n; j++) a0 += nf[esrc[st + j] * 64 + lane];
    }
    s_hn[r][lane] = (a0 + a1 + a2 + a3) * __builtin_amdgcn_rcpf(fmaxf((float)n, 1.f));
  }
  __syncthreads();
  int r = tid & 31;
  int c0 = (tid >> 5) * 4;
  float accs[4] = {0.f, 0.f, 0.f, 0.f};
  for (int k = 0; k < IN_DIM; k++) {
    float a = s_nf[r][k];
    float b = s_hn[r][k];
    float4 w1 = *(const float4*)&Wsc[k * 64 + c0];
    float4 w2 = *(const float4*)&Wnc[k * 64 + c0];
    accs[0] += a * w1.x + b * w2.x;
    accs[1] += a * w1.y + b * w2.y;
    accs[2] += a * w1.z + b * w2.z;
    accs[3] += a * w1.w + b * w2.w;
  }
  int node = node0 + r;
  if (node < N_NODES) {
    #pragma unroll
    for (int i = 0; i < 4; i++)
      out1[(size_t)node * 64 + c0 + i] = accs[i] + bc1[c0 + i];
  }
}

// ---------------- fused LSTM (8 steps) + classifier, W in registers ----------------
// R9 structure with LB 64 -> 32 (halves scheduling tail; c_st/xp halve) and
// sched_barrier fences removed (let the compiler pipeline the 2 row passes;
// ~60 regs of slack under the 256 budget).
#define LB 32
__global__ __launch_bounds__(512, 2) void lstm_kernel(
    const float* __restrict__ hist,          // [N][8][128] f32
    const unsigned short* __restrict__ Wt2,  // frag-ordered bf16
    const unsigned short* __restrict__ Wc2,  // frag-ordered bf16
    const float* __restrict__ b_lstm,        // [512]
    const float* __restrict__ out1,          // [N][64] fp32 (classifier partial)
    float* __restrict__ out)                 // [N][64]
{
  __shared__ alignas(16) unsigned short Abuf[2][LB * 256];  // 2 x 16KB

  const int tid = threadIdx.x;
  const int lane = tid & 63;
  const int w = tid >> 6;
  const int l15 = lane & 15;
  const int l4 = lane >> 4;
  const int base = blockIdx.x * LB;
  const int jj = w * 16 + l15;     // hidden unit owned by this lane

  // persistent B fragments: Bfr[g][kk]  (128 VGPR)
  short8 Bfr[4][8];
  #pragma unroll
  for (int g = 0; g < 4; g++)
    #pragma unroll
    for (int kk = 0; kk < 8; kk++)
      Bfr[g][kk] = *(const short8*)&Wt2[((w * 32 + g * 8 + kk) * 64 + lane) * 8];

  const float bi  = b_lstm[jj];
  const float bf_ = b_lstm[128 + jj];
  const float bg  = b_lstm[256 + jj];
  const float bo  = b_lstm[384 + jj];

  float c_st[8];
  #pragma unroll
  for (int i = 0; i < 8; i++) c_st[i] = 0.f;

  // prologue: zero h-region of buf0, stage x(0); 512 units, one per thread
  {
    int row = tid >> 4;
    int kb = tid & 15;
    short8 z = {0,0,0,0,0,0,0,0};
    *(short8*)&Abuf[0][row * 256 + 128 + kb * 8] = z;
    int node = base + row;
    float4 x0 = make_float4(0.f,0.f,0.f,0.f), x1 = make_float4(0.f,0.f,0.f,0.f);
    if (node < N_NODES) {
      const float4* p = (const float4*)&hist[(size_t)node * (T_HIST * HID) + kb * 8];
      x0 = p[0]; x1 = p[1];
    }
    int sb = (kb & 8) | ((kb & 7) ^ (row & 7));
    *(short8*)&Abuf[0][row * 256 + sb * 8] = cvt8(x0, x1);
  }
  __syncthreads();

  float4 xpa, xpb;  // prefetch regs (8 VGPR)
  const int srow = tid >> 4, skb = tid & 15;

  // ---- steps 0..6 ----
  #pragma unroll
  for (int t = 0; t < T_HIST - 1; t++) {
    unsigned short* Acur = &Abuf[t & 1][0];
    unsigned short* Anxt = &Abuf[(t & 1) ^ 1][0];

    // issue x(t+1) global loads early: latency hides under MFMA phase
    {
      int node = base + srow;
      if (node < N_NODES) {
        const float4* p = (const float4*)&hist[(size_t)node * (T_HIST * HID) + (t + 1) * HID + skb * 8];
        xpa = p[0]; xpb = p[1];
      } else {
        xpa = make_float4(0.f,0.f,0.f,0.f);
        xpb = make_float4(0.f,0.f,0.f,0.f);
      }
    }

    // 2 row-block passes; acc (16 VGPR) dies at end of each pass
    #pragma unroll
    for (int rb = 0; rb < 2; rb++) {
      f32x4 acc[4];
      #pragma unroll
      for (int g = 0; g < 4; g++) { f32x4 z = {0.f,0.f,0.f,0.f}; acc[g] = z; }
      #pragma unroll
      for (int kk = 0; kk < 8; kk++) {
        int row = rb * 16 + l15;
        int kb = kk * 4 + l4;
        int sb = (kb & 24) | ((kb & 7) ^ (row & 7));
        short8 a = *(const short8*)&Acur[row * 256 + sb * 8];
        #pragma unroll
        for (int g = 0; g < 4; g++)
          acc[g] = __builtin_amdgcn_mfma_f32_16x16x32_bf16(a, Bfr[g][kk], acc[g], 0, 0, 0);
      }
      // cell update for this row block; h -> Anxt h-region
      #pragma unroll
      for (int reg = 0; reg < 4; reg++) {
        int r = rb * 4 + reg;
        float gi = sigm(acc[0][reg] + bi);
        float gf = sigm(acc[1][reg] + bf_);
        float gg = tanh_f(acc[2][reg] + bg);
        float go = sigm(acc[3][reg] + bo);
        float c = gf * c_st[r] + gi * gg;
        c_st[r] = c;
        float h = go * tanh_f(c);
        int row = rb * 16 + l4 * 4 + reg;
        int kb = 16 + (jj >> 3);
        int sb = (kb & 24) | ((kb & 7) ^ (row & 7));
        Anxt[row * 256 + sb * 8 + (jj & 7)] = f2bf(h);
      }
    }

    // write staged x(t+1) into next buffer's x-region
    {
      int sb = (skb & 8) | ((skb & 7) ^ (srow & 7));
      *(short8*)&Anxt[srow * 256 + sb * 8] = cvt8(xpa, xpb);
    }
    __syncthreads();   // single barrier per step
  }

  // ---- t = 7 (peeled): final step; write h into x-region of Abuf[0] ----
  {
    unsigned short* Acur = &Abuf[1][0];
    unsigned short* Anxt = &Abuf[0][0];

    #pragma unroll
    for (int rb = 0; rb < 2; rb++) {
      f32x4 acc[4];
      #pragma unroll
      for (int g = 0; g < 4; g++) { f32x4 z = {0.f,0.f,0.f,0.f}; acc[g] = z; }
      #pragma unroll
      for (int kk = 0; kk < 8; kk++) {
        int row = rb * 16 + l15;
        int kb = kk * 4 + l4;
        int sb = (kb & 24) | ((kb & 7) ^ (row & 7));
        short8 a = *(const short8*)&Acur[row * 256 + sb * 8];
        #pragma unroll
        for (int g = 0; g < 4; g++)
          acc[g] = __builtin_amdgcn_mfma_f32_16x16x32_bf16(a, Bfr[g][kk], acc[g], 0, 0, 0);
      }
      #pragma unroll
      for (int reg = 0; reg < 4; reg++) {
        int r = rb * 4 + reg;
        float gi = sigm(acc[0][reg] + bi);
        float gf = sigm(acc[1][reg] + bf_);
        float gg = tanh_f(acc[2][reg] + bg);
        float go = sigm(acc[3][reg] + bo);
        float c = gf * c_st[r] + gi * gg;
        float h = go * tanh_f(c);
        int row = rb * 16 + l4 * 4 + reg;
        int kb = jj >> 3;
        int sb = (kb & 8) | ((kb & 7) ^ (row & 7));
        Anxt[row * 256 + sb * 8 + (jj & 7)] = f2bf(h);
      }
    }
    __syncthreads();

    // classifier: out = h_temp @ W_cls + out1; one frag per wave (Bfr dead)
    {
      int rbo = w >> 2, cbo = w & 3;
      int col = cbo * 16 + l15;
      float ov[4];
      #pragma unroll
      for (int reg = 0; reg < 4; reg++) {
        int row = rbo * 16 + l4 * 4 + reg;
        int node = base + row;
        ov[reg] = (node < N_NODES) ? out1[(size_t)node * OUT_DIM + col] : 0.f;
      }
      f32x4 o = {0.f, 0.f, 0.f, 0.f};
      #pragma unroll
      for (int kk = 0; kk < 4; kk++) {
        short8 bv = *(const short8*)&Wc2[((cbo * 4 + kk) * 64 + lane) * 8];
        int row = rbo * 16 + l15;
        int kb = kk * 4 + l4;
        int sb = (kb & 8) | ((kb & 7) ^ (row & 7));
        short8 a = *(const short8*)&Anxt[row * 256 + sb * 8];
        o = __builtin_amdgcn_mfma_f32_16x16x32_bf16(a, bv, o, 0, 0, 0);
      }
      #pragma unroll
      for (int reg = 0; reg < 4; reg++) {
        int row = rbo * 16 + l4 * 4 + reg;
        int node = base + row;
        if (node < N_NODES) out[(size_t)node * OUT_DIM + col] = o[reg] + ov[reg];
      }
    }
  }
}

// ---------------- launch ----------------
extern "C" void kernel_launch(void* const* d_in, const int* in_sizes, int n_in,
                              void* d_out, int out_size, void* d_ws, size_t ws_size,
                              hipStream_t stream) {
  (void)in_sizes; (void)n_in; (void)out_size; (void)ws_size;
  const float* node_feats = (const float*)d_in[0];
  const float* hist       = (const float*)d_in[1];
  const int*   src        = (const int*)d_in[2];
  const int*   dst        = (const int*)d_in[3];
  const float* W_self     = (const float*)d_in[4];
  const float* W_neigh    = (const float*)d_in[5];
  const float* b_sage     = (const float*)d_in[6];
  const float* w_ih       = (const float*)d_in[7];
  const float* w_hh       = (const float*)d_in[8];
  const float* b_lstm     = (const float*)d_in[9];
  const float* W_cls      = (const float*)d_in[10];
  const float* b_cls      = (const float*)d_in[11];
  float* out = (float*)d_out;

  char* ws = (char*)d_ws;
  int* cnt        = (int*)(ws);                        // 200,192
  int* lexcl      = (int*)(ws + 200192);               // -> 400,384
  int* rowstart   = (int*)(ws + 400384);               // -> 600,576
  int* cursor     = (int*)(ws + 600576);               // -> 800,768
  int* btot       = (int*)(ws + 800768);               // -> 801,792
  int* esrc       = (int*)(ws + 801792);               // -> 4,001,792
  float* out1     = (float*)(ws + 4001792);            // -> 16,801,792
  unsigned short* Wt2 = (unsigned short*)(ws + 16801792);  // -> 17,063,936
  unsigned short* Wc2 = (unsigned short*)(ws + 17063936);  // -> 17,080,320
  float* Wsc      = (float*)(ws + 17080320);           // -> 17,096,704
  float* Wnc      = (float*)(ws + 17096704);           // -> 17,113,088
  float* bc1      = (float*)(ws + 17113088);           // -> 17,113,344

  hipMemsetAsync(cnt, 0, 200000, stream);
  pc_kernel<<<1024, 256, 0, stream>>>(w_ih, w_hh, W_cls, W_self, W_neigh, b_sage, b_cls,
                                      dst, Wt2, Wc2, Wsc, Wnc, bc1, cnt);
  scan1_kernel<<<NB_SCAN, 256, 0, stream>>>(cnt, lexcl, btot);
  scan3_kernel<<<NB_SCAN, 1024, 0, stream>>>(lexcl, btot, rowstart, cursor);
  fill_kernel<<<(N_EDGES + 255) / 256, 256, 0, stream>>>(src, dst, cursor, esrc);
  hstruct_kernel<<<(N_NODES + HS_TILE - 1) / HS_TILE, 512, 0, stream>>>(
      node_feats, esrc, rowstart, cnt, Wsc, Wnc, bc1, out1);
  lstm_kernel<<<(N_NODES + LB - 1) / LB, 512, 0, stream>>>(
      hist, Wt2, Wc2, b_lstm, out1, out);
}